// Round 10
// baseline (201.094 us; speedup 1.0000x reference)
//
#include <hip/hip_runtime.h>
#include <hip/hip_bf16.h>
#include <hip/hip_fp16.h>
#include <cstdint>

// B=8, S=2048, D=256 fused attention block, fp32 in/out.
// Round 10 (= round 9 candidate resubmit; infra ate the bench):
// attn rebuilt for occupancy + MFMA density:
//   4-wave blocks (QBLK=64), KVBLK=64, K->LDS (2-barrier prefetch),
//   V read direct from L2 ([b][d][s] layout), XCD-swizzled batch locality,
//   hoisted addressing, NSPLIT=2 split-K (combine unchanged).
// GEMM/LN/cast stages unchanged from round 8.

#define RROWS 16384
#define DD 256
#define SEQ 2048
#define NB 8
#define NSPLIT 2
#define QBLK 64
#define KVBLK 64
#define NT_SPLIT (SEQ / KVBLK / NSPLIT)   // 16 tiles per split

typedef _Float16 f16x8 __attribute__((ext_vector_type(8)));
typedef _Float16 f16x4 __attribute__((ext_vector_type(4)));
typedef float f32x4 __attribute__((ext_vector_type(4)));

// ---------------------------------------------------------------------------
// casts
// ---------------------------------------------------------------------------
__global__ __launch_bounds__(256) void cast_x_kernel(
    const float* __restrict__ src, _Float16* __restrict__ dst)
{
  const size_t i = ((size_t)blockIdx.x * 256 + threadIdx.x) * 8;
  float4 a = *(const float4*)&src[i];
  float4 b = *(const float4*)&src[i + 4];
  f16x8 h = { (_Float16)a.x, (_Float16)a.y, (_Float16)a.z, (_Float16)a.w,
              (_Float16)b.x, (_Float16)b.y, (_Float16)b.z, (_Float16)b.w };
  *(f16x8*)&dst[i] = h;
}

__global__ __launch_bounds__(256) void cast_w_kernel(
    const float* __restrict__ w0, const float* __restrict__ w1,
    const float* __restrict__ w2, const float* __restrict__ w3,
    _Float16* __restrict__ dst)
{
  const float* srcs[4] = {w0, w1, w2, w3};
  const float* src = srcs[blockIdx.y];
  _Float16* d = dst + (size_t)blockIdx.y * 65536;
  const size_t i = ((size_t)blockIdx.x * 256 + threadIdx.x) * 8;
  float4 a = *(const float4*)&src[i];
  float4 b = *(const float4*)&src[i + 4];
  f16x8 h = { (_Float16)a.x, (_Float16)a.y, (_Float16)a.z, (_Float16)a.w,
              (_Float16)b.x, (_Float16)b.y, (_Float16)b.z, (_Float16)b.w };
  *(f16x8*)&d[i] = h;
}

// ---------------------------------------------------------------------------
// fp16 MFMA GEMM (unchanged from round 8): 64x128 tile, K=256.
// MODE 0: f32 out + res.  MODE 1: f16 out.  MODE 2: f16 transposed [b][e][s].
// ---------------------------------------------------------------------------
template <int MODE>
__global__ __launch_bounds__(256) void gemm16_kernel(
    const _Float16* __restrict__ X, const _Float16* __restrict__ W,
    const float* __restrict__ bias, const float* __restrict__ res,
    void* __restrict__ outv)
{
  __shared__ _Float16 smem[128 * 264];
  const int t     = threadIdx.x;
  const int lane  = t & 63;
  const int w     = t >> 6;
  const int rows0 = blockIdx.x * 64;
  const int col0  = blockIdx.y * 128;
  const int lr = lane & 15;
  const int lg = lane >> 4;

#pragma unroll
  for (int i = 0; i < 16; ++i) {
    int ch = i * 256 + t;
    int er = ch >> 5, kc = (ch & 31) * 8;
    *(f16x8*)&smem[er * 264 + kc] = *(const f16x8*)&W[(size_t)(col0 + er) * DD + kc];
  }

  f16x8 qf[8];
  {
    const _Float16* xrow = X + (size_t)(rows0 + w * 16 + lr) * DD;
#pragma unroll
    for (int ks = 0; ks < 8; ++ks)
      qf[ks] = *(const f16x8*)(xrow + ks * 32 + lg * 8);
  }
  __syncthreads();

  f32x4 acc[8];
#pragma unroll
  for (int i = 0; i < 8; ++i) acc[i] = (f32x4){0.f, 0.f, 0.f, 0.f};

#pragma unroll
  for (int ct = 0; ct < 8; ++ct)
#pragma unroll
    for (int ks = 0; ks < 8; ++ks) {
      f16x8 wf = *(const f16x8*)&smem[(ct * 16 + lr) * 264 + ks * 32 + lg * 8];
      acc[ct] = __builtin_amdgcn_mfma_f32_16x16x32_f16(qf[ks], wf, acc[ct], 0, 0, 0);
    }

  float bf[8];
#pragma unroll
  for (int ct = 0; ct < 8; ++ct) bf[ct] = bias[col0 + ct * 16 + lr];

  if constexpr (MODE == 0) {
    float* out = (float*)outv;
#pragma unroll
    for (int ct = 0; ct < 8; ++ct)
#pragma unroll
      for (int j = 0; j < 4; ++j) {
        int r = rows0 + w * 16 + lg * 4 + j;
        int c = col0 + ct * 16 + lr;
        out[(size_t)r * DD + c] = acc[ct][j] + bf[ct] + res[(size_t)r * DD + c];
      }
  } else if constexpr (MODE == 1) {
    _Float16* out = (_Float16*)outv;
#pragma unroll
    for (int ct = 0; ct < 8; ++ct)
#pragma unroll
      for (int j = 0; j < 4; ++j) {
        int r = rows0 + w * 16 + lg * 4 + j;
        out[(size_t)r * DD + col0 + ct * 16 + lr] = (_Float16)(acc[ct][j] + bf[ct]);
      }
  } else {
    __syncthreads();
    _Float16* T = smem;   // reuse: [128 e][72 s-pitch]
#pragma unroll
    for (int ct = 0; ct < 8; ++ct)
#pragma unroll
      for (int j = 0; j < 4; ++j)
        T[(ct * 16 + lr) * 72 + (w * 16 + lg * 4 + j)] = (_Float16)(acc[ct][j] + bf[ct]);
    __syncthreads();
    _Float16* out = (_Float16*)outv;
    const int bIdx = rows0 >> 11;
    const int s0   = rows0 & (SEQ - 1);
#pragma unroll
    for (int p = 0; p < 4; ++p) {
      int ch = p * 256 + t;
      int e = ch >> 3, sc = (ch & 7) * 8;
      *(f16x8*)&out[((size_t)bIdx * DD + col0 + e) * SEQ + s0 + sc] =
          *(const f16x8*)&T[e * 72 + sc];
    }
  }
}

// ---------------------------------------------------------------------------
// Split-K MFMA flash attention, v2.
// Block = 256 thr (4 waves), QBLK=64 (wave w owns rows q0+w*16..+15),
// KVBLK=64, NSPLIT=2. 1-D grid of 512, lid&7 = batch (XCD L2 locality).
// K staged in LDS [64][264] (2-way-bank-free), reg-prefetched; V fragments
// read directly from VtG[b][d][s] (L2) with a 2-stage dt pipeline; P via
// per-wave LDS tile [16][72]. fp32 softmax/accum. 64 MFMA/wave/tile.
// ---------------------------------------------------------------------------
__global__ __launch_bounds__(256, 2) void attn_partial_kernel(
    const _Float16* __restrict__ Q, const _Float16* __restrict__ K,
    const _Float16* __restrict__ VT, _Float16* __restrict__ Op,
    float* __restrict__ Mp, float* __restrict__ Lp)
{
  __shared__ _Float16 Ks[KVBLK][264];     // 33.8 KB
  __shared__ _Float16 Ps[4][16][72];      //  9.2 KB

  const int t     = threadIdx.x;
  const int lane  = t & 63;
  const int w     = t >> 6;
  const int lid   = blockIdx.x;
  const int b     = lid & 7;              // batch == XCD slot
  const int inner = lid >> 3;             // 0..63
  const int split = inner & 1;
  const int q0    = (inner >> 1) * QBLK;
  const int kt0   = split * NT_SPLIT;
  const int lr    = lane & 15;
  const int lg    = lane >> 4;

  // Q fragments: wave's 16 rows x K=256
  f16x8 qf[8];
  {
    const _Float16* qrow = Q + (size_t)b * SEQ * DD + (size_t)(q0 + w * 16 + lr) * DD;
#pragma unroll
    for (int ks = 0; ks < 8; ++ks)
      qf[ks] = *(const f16x8*)(qrow + ks * 32 + lg * 8);
  }

  // hoisted staging pointers
  const _Float16* krun = K + (size_t)b * SEQ * DD + (size_t)kt0 * KVBLK * DD
                         + (t >> 5) * DD + (t & 31) * 8;
  _Float16* klds = &Ks[t >> 5][(t & 31) * 8];
  const _Float16* vrun = VT + (size_t)b * DD * SEQ + (size_t)lr * SEQ
                         + kt0 * KVBLK + lg * 8;

  f32x4 cacc[16];
#pragma unroll
  for (int i = 0; i < 16; ++i) cacc[i] = (f32x4){0.f, 0.f, 0.f, 0.f};
  float mrun[4] = {-1e30f, -1e30f, -1e30f, -1e30f};
  float lrun[4] = {0.f, 0.f, 0.f, 0.f};

  f16x8 kreg[8];
  // prologue: stage tile kt0
#pragma unroll
  for (int i = 0; i < 8; ++i) kreg[i] = *(const f16x8*)(krun + (size_t)i * 8 * DD);
#pragma unroll
  for (int i = 0; i < 8; ++i) *(f16x8*)(klds + i * 8 * 264) = kreg[i];
  __syncthreads();

  for (int kt = 0; kt < NT_SPLIT; ++kt) {
    const bool pre = (kt + 1 < NT_SPLIT);
    if (pre) {
      krun += (size_t)KVBLK * DD;
#pragma unroll
      for (int i = 0; i < 8; ++i) kreg[i] = *(const f16x8*)(krun + (size_t)i * 8 * DD);
    }

    // ---- S = Q.K^T : 4 col-tiles x 8 k-steps (32 MFMA, 4 indep chains) ----
    f32x4 sc[4];
#pragma unroll
    for (int ct = 0; ct < 4; ++ct) sc[ct] = (f32x4){0.f, 0.f, 0.f, 0.f};
#pragma unroll
    for (int ct = 0; ct < 4; ++ct)
#pragma unroll
      for (int ks = 0; ks < 8; ++ks) {
        f16x8 kf = *(const f16x8*)(&Ks[ct * 16 + lr][ks * 32 + lg * 8]);
        sc[ct] = __builtin_amdgcn_mfma_f32_16x16x32_f16(qf[ks], kf, sc[ct], 0, 0, 0);
      }

    __syncthreads();                 // all waves done reading Ks
    if (pre) {                       // publish next K; retires under softmax/PV
#pragma unroll
      for (int i = 0; i < 8; ++i) *(f16x8*)(klds + i * 8 * 264) = kreg[i];
    }

    // ---- online softmax (lane owns 4 q-rows, 4 k-cols) --------------------
    float scl[4];
#pragma unroll
    for (int j = 0; j < 4; ++j) {
      float tm = fmaxf(fmaxf(sc[0][j], sc[1][j]), fmaxf(sc[2][j], sc[3][j]));
      tm = fmaxf(tm, __shfl_xor(tm, 1, 16));
      tm = fmaxf(tm, __shfl_xor(tm, 2, 16));
      tm = fmaxf(tm, __shfl_xor(tm, 4, 16));
      tm = fmaxf(tm, __shfl_xor(tm, 8, 16));
      float mnew = fmaxf(mrun[j], tm);
      scl[j] = __expf(mrun[j] - mnew);
      float ps = 0.f;
#pragma unroll
      for (int ct = 0; ct < 4; ++ct) {
        float p = __expf(sc[ct][j] - mnew);
        sc[ct][j] = p; ps += p;
      }
      ps += __shfl_xor(ps, 1, 16);
      ps += __shfl_xor(ps, 2, 16);
      ps += __shfl_xor(ps, 4, 16);
      ps += __shfl_xor(ps, 8, 16);
      lrun[j] = lrun[j] * scl[j] + ps;
      mrun[j] = mnew;
    }

    // ---- P -> per-wave LDS tile (fp16) ------------------------------------
#pragma unroll
    for (int ct = 0; ct < 4; ++ct)
#pragma unroll
      for (int j = 0; j < 4; ++j)
        Ps[w][lg * 4 + j][ct * 16 + lr] = (_Float16)sc[ct][j];

    // ---- rescale ctx ------------------------------------------------------
#pragma unroll
    for (int dt = 0; dt < 16; ++dt)
#pragma unroll
      for (int j = 0; j < 4; ++j) cacc[dt][j] *= scl[j];

    // ---- ctx += P.V : V fragments from L2, 2-stage dt pipeline ------------
    f16x8 pa0 = *(const f16x8*)(&Ps[w][lr][lg * 8]);
    f16x8 pa1 = *(const f16x8*)(&Ps[w][lr][32 + lg * 8]);
    f16x8 va = *(const f16x8*)(vrun);
    f16x8 vb = *(const f16x8*)(vrun + 32);
#pragma unroll
    for (int dt = 0; dt < 16; ++dt) {
      const int dn = (dt + 1 < 16) ? dt + 1 : 15;
      f16x8 na = *(const f16x8*)(vrun + (size_t)dn * 16 * SEQ);
      f16x8 nb = *(const f16x8*)(vrun + (size_t)dn * 16 * SEQ + 32);
      cacc[dt] = __builtin_amdgcn_mfma_f32_16x16x32_f16(pa0, va, cacc[dt], 0, 0, 0);
      cacc[dt] = __builtin_amdgcn_mfma_f32_16x16x32_f16(pa1, vb, cacc[dt], 0, 0, 0);
      va = na; vb = nb;
    }
    vrun += KVBLK;

    __syncthreads();                 // staged K visible before next QK^T
  }

  // ---- epilogue: UNNORMALIZED partial ctx (f16) + m/l (f32) ---------------
  const size_t Rbase = (size_t)b * SEQ + q0 + w * 16;
#pragma unroll
  for (int j = 0; j < 4; ++j) {
    size_t R = Rbase + lg * 4 + j;
    if (lr == 0) {
      Mp[(size_t)split * RROWS + R] = mrun[j];
      Lp[(size_t)split * RROWS + R] = lrun[j];
    }
#pragma unroll
    for (int dt = 0; dt < 16; ++dt)
      Op[((size_t)split * RROWS + R) * DD + dt * 16 + lr] = (_Float16)cacc[dt][j];
  }
}

// ---------------------------------------------------------------------------
// Combine the NSPLIT partials: ctx = (sum_i e^{mi-m*} Oi) / (sum_i e^{mi-m*} li)
// ---------------------------------------------------------------------------
__global__ __launch_bounds__(256) void attn_combine_kernel(
    const _Float16* __restrict__ Op, const float* __restrict__ Mp,
    const float* __restrict__ Lp, _Float16* __restrict__ ctx)
{
  const int lane = threadIdx.x & 63;
  const int w    = threadIdx.x >> 6;
  const size_t R = (size_t)blockIdx.x * 4 + w;
  float m0 = Mp[R], m1 = Mp[RROWS + R];
  float l0 = Lp[R], l1 = Lp[RROWS + R];
  float ms = fmaxf(m0, m1);
  float w0 = __expf(m0 - ms), w1 = __expf(m1 - ms);
  float linv = 1.0f / (w0 * l0 + w1 * l1);
  w0 *= linv; w1 *= linv;
  f16x4 o0 = *(const f16x4*)&Op[R * DD + lane * 4];
  f16x4 o1 = *(const f16x4*)&Op[((size_t)RROWS + R) * DD + lane * 4];
  f16x4 o;
#pragma unroll
  for (int i = 0; i < 4; ++i)
    o[i] = (_Float16)(w0 * (float)o0[i] + w1 * (float)o1[i]);
  *(f16x4*)&ctx[R * DD + lane * 4] = o;
}

// ---------------------------------------------------------------------------
// LayerNorm over last dim (256). One wave per row, 4 rows per block.
// ---------------------------------------------------------------------------
__global__ __launch_bounds__(256) void ln_kernel(
    const float* __restrict__ H, const float* __restrict__ g,
    const float* __restrict__ b, float* __restrict__ out)
{
  const int lane = threadIdx.x & 63;
  const int w    = threadIdx.x >> 6;
  const int r    = blockIdx.x * 4 + w;
  const size_t rowoff = (size_t)r * DD;
  float4 h4 = *(const float4*)&H[rowoff + lane * 4];
  float s = h4.x + h4.y + h4.z + h4.w;
#pragma unroll
  for (int m = 1; m < 64; m <<= 1) s += __shfl_xor(s, m, 64);
  float mu = s * (1.0f / 256.0f);
  float dx = h4.x - mu, dy = h4.y - mu, dz = h4.z - mu, dw = h4.w - mu;
  float v = dx*dx + dy*dy + dz*dz + dw*dw;
#pragma unroll
  for (int m = 1; m < 64; m <<= 1) v += __shfl_xor(v, m, 64);
  float rs = rsqrtf(v * (1.0f / 256.0f) + 1e-5f);
  float4 g4 = *(const float4*)&g[lane * 4];
  float4 b4 = *(const float4*)&b[lane * 4];
  float4 o;
  o.x = dx * rs * g4.x + b4.x;
  o.y = dy * rs * g4.y + b4.y;
  o.z = dz * rs * g4.z + b4.z;
  o.w = dw * rs * g4.w + b4.w;
  *(float4*)&out[rowoff + lane * 4] = o;
}

// ---------------------------------------------------------------------------
extern "C" void kernel_launch(void* const* d_in, const int* in_sizes, int n_in,
                              void* d_out, int out_size, void* d_ws, size_t ws_size,
                              hipStream_t stream) {
  const float* x  = (const float*)d_in[0];
  const float* Wq = (const float*)d_in[1];
  const float* bq = (const float*)d_in[2];
  const float* Wk = (const float*)d_in[3];
  const float* bk = (const float*)d_in[4];
  const float* Wv = (const float*)d_in[5];
  const float* bv = (const float*)d_in[6];
  const float* Wd = (const float*)d_in[7];
  const float* bd = (const float*)d_in[8];
  const float* g  = (const float*)d_in[9];
  const float* b  = (const float*)d_in[10];
  float* out = (float*)d_out;

  const size_t RD = (size_t)RROWS * DD;         // 4 M elements
  _Float16* ws16 = (_Float16*)d_ws;
  _Float16* xh   = ws16;                        //  8 MB
  _Float16* Qh   = ws16 + RD;                   //  8 MB; later ctx
  _Float16* Kh   = ws16 + 2 * RD;               //  8 MB
  _Float16* VtG  = ws16 + 3 * RD;               //  8 MB, [b][d][s]
  _Float16* Op   = ws16 + 4 * RD;               // 16 MB
  float*    Hf   = (float*)(ws16 + 4 * RD);     // 16 MB overlays Op (dead)
  float*    Mp   = (float*)(ws16 + 6 * RD);     // 128 KB
  float*    Lp   = Mp + (size_t)NSPLIT * RROWS; // 128 KB
  _Float16* Wh   = (_Float16*)(Lp + (size_t)NSPLIT * RROWS);  // 512 KB
  _Float16* ctxh = Qh;

  cast_x_kernel<<<2048, 256, 0, stream>>>(x, xh);
  cast_w_kernel<<<dim3(32, 4), 256, 0, stream>>>(Wq, Wk, Wv, Wd, Wh);

  dim3 gg(RROWS / 64, DD / 128);   // (256, 2)
  gemm16_kernel<1><<<gg, 256, 0, stream>>>(xh, Wh,             bq, nullptr, Qh);
  gemm16_kernel<1><<<gg, 256, 0, stream>>>(xh, Wh + 65536,     bk, nullptr, Kh);
  gemm16_kernel<2><<<gg, 256, 0, stream>>>(xh, Wh + 2 * 65536, bv, nullptr, VtG);

  // 1-D grid: lid&7 = batch, (lid>>3)&1 = split, lid>>4 = q-tile.
  // 32 qtiles * 2 splits * 8 batches = 512 blocks.
  attn_partial_kernel<<<dim3((SEQ / QBLK) * NSPLIT * NB), 256, 0, stream>>>(
      Qh, Kh, VtG, Op, Mp, Lp);
  attn_combine_kernel<<<RROWS / 4, 256, 0, stream>>>(Op, Mp, Lp, ctxh);

  gemm16_kernel<0><<<gg, 256, 0, stream>>>(ctxh, Wh + 3 * 65536, bd, x, Hf);

  ln_kernel<<<RROWS / 4, 256, 0, stream>>>(Hf, g, b, out);
}

// Round 12
// 125.347 us; speedup vs baseline: 1.6043x; 1.6043x over previous
//
#include <hip/hip_runtime.h>
#include <hip/hip_bf16.h>
#include <hip/hip_fp16.h>
#include <cstdint>

// B=8, S=2048, D=256 fused attention block, fp32 in/out.
// Round 12 (= round 11 candidate resubmit; infra ate the bench):
// V de-scatter. V stored TILED [b][s/64][256 d][64 s] (coalesced writes in
// gemm MODE2, coalesced 1KB wave-loads in attn), V staged in LDS Vt[256][72];
// issue-early/write-late K+V staging (loads at tile top, LDS publish after
// PV). KVBLK=64, 4-wave blocks, NSPLIT=2, XCD batch locality.

#define RROWS 16384
#define DD 256
#define SEQ 2048
#define NB 8
#define NSPLIT 2
#define QBLK 64
#define KVBLK 64
#define NT_SPLIT (SEQ / KVBLK / NSPLIT)   // 16 tiles per split
#define NTILES (SEQ / KVBLK)              // 32 V s-tiles per batch

typedef _Float16 f16x8 __attribute__((ext_vector_type(8)));
typedef _Float16 f16x4 __attribute__((ext_vector_type(4)));
typedef float f32x4 __attribute__((ext_vector_type(4)));

// ---------------------------------------------------------------------------
// casts
// ---------------------------------------------------------------------------
__global__ __launch_bounds__(256) void cast_x_kernel(
    const float* __restrict__ src, _Float16* __restrict__ dst)
{
  const size_t i = ((size_t)blockIdx.x * 256 + threadIdx.x) * 8;
  float4 a = *(const float4*)&src[i];
  float4 b = *(const float4*)&src[i + 4];
  f16x8 h = { (_Float16)a.x, (_Float16)a.y, (_Float16)a.z, (_Float16)a.w,
              (_Float16)b.x, (_Float16)b.y, (_Float16)b.z, (_Float16)b.w };
  *(f16x8*)&dst[i] = h;
}

__global__ __launch_bounds__(256) void cast_w_kernel(
    const float* __restrict__ w0, const float* __restrict__ w1,
    const float* __restrict__ w2, const float* __restrict__ w3,
    _Float16* __restrict__ dst)
{
  const float* srcs[4] = {w0, w1, w2, w3};
  const float* src = srcs[blockIdx.y];
  _Float16* d = dst + (size_t)blockIdx.y * 65536;
  const size_t i = ((size_t)blockIdx.x * 256 + threadIdx.x) * 8;
  float4 a = *(const float4*)&src[i];
  float4 b = *(const float4*)&src[i + 4];
  f16x8 h = { (_Float16)a.x, (_Float16)a.y, (_Float16)a.z, (_Float16)a.w,
              (_Float16)b.x, (_Float16)b.y, (_Float16)b.z, (_Float16)b.w };
  *(f16x8*)&d[i] = h;
}

// ---------------------------------------------------------------------------
// fp16 MFMA GEMM: 64x128 tile, K=256.
// MODE 0: f32 out + res.  MODE 1: f16 out.
// MODE 2: f16 out TILED [b][s/64][256 d][64 s] via LDS transpose (coalesced).
// ---------------------------------------------------------------------------
template <int MODE>
__global__ __launch_bounds__(256) void gemm16_kernel(
    const _Float16* __restrict__ X, const _Float16* __restrict__ W,
    const float* __restrict__ bias, const float* __restrict__ res,
    void* __restrict__ outv)
{
  __shared__ _Float16 smem[128 * 264];
  const int t     = threadIdx.x;
  const int lane  = t & 63;
  const int w     = t >> 6;
  const int rows0 = blockIdx.x * 64;
  const int col0  = blockIdx.y * 128;
  const int lr = lane & 15;
  const int lg = lane >> 4;

#pragma unroll
  for (int i = 0; i < 16; ++i) {
    int ch = i * 256 + t;
    int er = ch >> 5, kc = (ch & 31) * 8;
    *(f16x8*)&smem[er * 264 + kc] = *(const f16x8*)&W[(size_t)(col0 + er) * DD + kc];
  }

  f16x8 qf[8];
  {
    const _Float16* xrow = X + (size_t)(rows0 + w * 16 + lr) * DD;
#pragma unroll
    for (int ks = 0; ks < 8; ++ks)
      qf[ks] = *(const f16x8*)(xrow + ks * 32 + lg * 8);
  }
  __syncthreads();

  f32x4 acc[8];
#pragma unroll
  for (int i = 0; i < 8; ++i) acc[i] = (f32x4){0.f, 0.f, 0.f, 0.f};

#pragma unroll
  for (int ct = 0; ct < 8; ++ct)
#pragma unroll
    for (int ks = 0; ks < 8; ++ks) {
      f16x8 wf = *(const f16x8*)&smem[(ct * 16 + lr) * 264 + ks * 32 + lg * 8];
      acc[ct] = __builtin_amdgcn_mfma_f32_16x16x32_f16(qf[ks], wf, acc[ct], 0, 0, 0);
    }

  float bf[8];
#pragma unroll
  for (int ct = 0; ct < 8; ++ct) bf[ct] = bias[col0 + ct * 16 + lr];

  if constexpr (MODE == 0) {
    float* out = (float*)outv;
#pragma unroll
    for (int ct = 0; ct < 8; ++ct)
#pragma unroll
      for (int j = 0; j < 4; ++j) {
        int r = rows0 + w * 16 + lg * 4 + j;
        int c = col0 + ct * 16 + lr;
        out[(size_t)r * DD + c] = acc[ct][j] + bf[ct] + res[(size_t)r * DD + c];
      }
  } else if constexpr (MODE == 1) {
    _Float16* out = (_Float16*)outv;
#pragma unroll
    for (int ct = 0; ct < 8; ++ct)
#pragma unroll
      for (int j = 0; j < 4; ++j) {
        int r = rows0 + w * 16 + lg * 4 + j;
        out[(size_t)r * DD + col0 + ct * 16 + lr] = (_Float16)(acc[ct][j] + bf[ct]);
      }
  } else {  // MODE 2: tiled V^T, [b][s/64][256 d][64 s]
    __syncthreads();
    _Float16* T = smem;   // reuse: [128 e][72 s-pitch]
#pragma unroll
    for (int ct = 0; ct < 8; ++ct)
#pragma unroll
      for (int j = 0; j < 4; ++j)
        T[(ct * 16 + lr) * 72 + (w * 16 + lg * 4 + j)] = (_Float16)(acc[ct][j] + bf[ct]);
    __syncthreads();
    _Float16* out = (_Float16*)outv;
    const int bIdx = rows0 >> 11;
    const int tIdx = (rows0 & (SEQ - 1)) >> 6;
    _Float16* base = out + (((size_t)bIdx * NTILES + tIdx) * DD + col0) * KVBLK;
#pragma unroll
    for (int p = 0; p < 4; ++p) {
      int ch = p * 256 + t;
      int e = ch >> 3, sc = (ch & 7) * 8;
      *(f16x8*)&base[(size_t)e * KVBLK + sc] = *(const f16x8*)&T[e * 72 + sc];
    }
  }
}

// ---------------------------------------------------------------------------
// Split-K MFMA flash attention, v3 (de-scattered V).
// Block = 256 thr (4 waves), QBLK=64, KVBLK=64, NSPLIT=2.
// 1-D grid of 512, lid&7 = batch (XCD L2 locality).
// K staged in LDS Ks[64][264]; V staged in LDS Vt[256][72] from the TILED
// global layout (1KB coalesced wave loads). Issue-early / write-late:
// loads for kt+1 issue at tile top, vmcnt drain + LDS publish after PV.
// ---------------------------------------------------------------------------
__global__ __launch_bounds__(256, 2) void attn_partial_kernel(
    const _Float16* __restrict__ Q, const _Float16* __restrict__ K,
    const _Float16* __restrict__ VT, _Float16* __restrict__ Op,
    float* __restrict__ Mp, float* __restrict__ Lp)
{
  __shared__ _Float16 Ks[KVBLK][264];     // 33.8 KB
  __shared__ _Float16 Vt[256][72];        // 36.9 KB
  __shared__ _Float16 Ps[4][16][72];      //  9.2 KB   (total 79.9 KB)

  const int t     = threadIdx.x;
  const int lane  = t & 63;
  const int w     = t >> 6;
  const int lid   = blockIdx.x;
  const int b     = lid & 7;              // batch == XCD slot
  const int inner = lid >> 3;             // 0..63
  const int split = inner & 1;
  const int q0    = (inner >> 1) * QBLK;
  const int kt0   = split * NT_SPLIT;
  const int lr    = lane & 15;
  const int lg    = lane >> 4;

  // Q fragments: wave's 16 rows x K=256
  f16x8 qf[8];
  {
    const _Float16* qrow = Q + (size_t)b * SEQ * DD + (size_t)(q0 + w * 16 + lr) * DD;
#pragma unroll
    for (int ks = 0; ks < 8; ++ks)
      qf[ks] = *(const f16x8*)(qrow + ks * 32 + lg * 8);
  }

  // hoisted staging pointers
  const _Float16* krun  = K + (size_t)b * SEQ * DD + (size_t)kt0 * KVBLK * DD
                          + (t >> 5) * DD + (t & 31) * 8;
  _Float16* klds = &Ks[t >> 5][(t & 31) * 8];
  const _Float16* vtile = VT + ((size_t)b * NTILES + kt0) * (DD * KVBLK)
                          + (size_t)t * 8;
  _Float16* vlds = &Vt[t >> 3][(t & 7) * 8];

  f32x4 cacc[16];
#pragma unroll
  for (int i = 0; i < 16; ++i) cacc[i] = (f32x4){0.f, 0.f, 0.f, 0.f};
  float mrun[4] = {-1e30f, -1e30f, -1e30f, -1e30f};
  float lrun[4] = {0.f, 0.f, 0.f, 0.f};

  f16x8 kreg[8], vreg[8];
  // ---- prologue: stage tile kt0 -------------------------------------------
#pragma unroll
  for (int i = 0; i < 8; ++i) kreg[i] = *(const f16x8*)(krun + (size_t)i * 8 * DD);
#pragma unroll
  for (int i = 0; i < 8; ++i) vreg[i] = *(const f16x8*)(vtile + i * 2048);
#pragma unroll
  for (int i = 0; i < 8; ++i) *(f16x8*)(klds + i * 8 * 264) = kreg[i];
#pragma unroll
  for (int i = 0; i < 8; ++i) *(f16x8*)(vlds + (size_t)i * 32 * 72) = vreg[i];
  __syncthreads();

  for (int kt = 0; kt < NT_SPLIT; ++kt) {
    const bool pre = (kt + 1 < NT_SPLIT);
    if (pre) {                                  // issue-early (T14)
      krun  += (size_t)KVBLK * DD;
      vtile += (size_t)DD * KVBLK;
#pragma unroll
      for (int i = 0; i < 8; ++i) kreg[i] = *(const f16x8*)(krun + (size_t)i * 8 * DD);
#pragma unroll
      for (int i = 0; i < 8; ++i) vreg[i] = *(const f16x8*)(vtile + i * 2048);
    }

    // ---- S = Q.K^T : 4 col-tiles x 8 k-steps ------------------------------
    f32x4 sc[4];
#pragma unroll
    for (int ct = 0; ct < 4; ++ct) sc[ct] = (f32x4){0.f, 0.f, 0.f, 0.f};
#pragma unroll
    for (int ct = 0; ct < 4; ++ct)
#pragma unroll
      for (int ks = 0; ks < 8; ++ks) {
        f16x8 kf = *(const f16x8*)(&Ks[ct * 16 + lr][ks * 32 + lg * 8]);
        sc[ct] = __builtin_amdgcn_mfma_f32_16x16x32_f16(qf[ks], kf, sc[ct], 0, 0, 0);
      }

    // ---- online softmax (lane owns 4 q-rows, 4 k-cols) --------------------
    float scl[4];
#pragma unroll
    for (int j = 0; j < 4; ++j) {
      float tm = fmaxf(fmaxf(sc[0][j], sc[1][j]), fmaxf(sc[2][j], sc[3][j]));
      tm = fmaxf(tm, __shfl_xor(tm, 1, 16));
      tm = fmaxf(tm, __shfl_xor(tm, 2, 16));
      tm = fmaxf(tm, __shfl_xor(tm, 4, 16));
      tm = fmaxf(tm, __shfl_xor(tm, 8, 16));
      float mnew = fmaxf(mrun[j], tm);
      scl[j] = __expf(mrun[j] - mnew);
      float ps = 0.f;
#pragma unroll
      for (int ct = 0; ct < 4; ++ct) {
        float p = __expf(sc[ct][j] - mnew);
        sc[ct][j] = p; ps += p;
      }
      ps += __shfl_xor(ps, 1, 16);
      ps += __shfl_xor(ps, 2, 16);
      ps += __shfl_xor(ps, 4, 16);
      ps += __shfl_xor(ps, 8, 16);
      lrun[j] = lrun[j] * scl[j] + ps;
      mrun[j] = mnew;
    }

    // ---- P -> per-wave LDS tile (fp16) ------------------------------------
#pragma unroll
    for (int ct = 0; ct < 4; ++ct)
#pragma unroll
      for (int j = 0; j < 4; ++j)
        Ps[w][lg * 4 + j][ct * 16 + lr] = (_Float16)sc[ct][j];

    // ---- rescale ctx ------------------------------------------------------
#pragma unroll
    for (int dt = 0; dt < 16; ++dt)
#pragma unroll
      for (int j = 0; j < 4; ++j) cacc[dt][j] *= scl[j];

    // ---- ctx += P.V from LDS: 16 d-tiles x 2 MFMA -------------------------
    f16x8 pa0 = *(const f16x8*)(&Ps[w][lr][lg * 8]);
    f16x8 pa1 = *(const f16x8*)(&Ps[w][lr][32 + lg * 8]);
#pragma unroll
    for (int dt = 0; dt < 16; ++dt) {
      f16x8 va = *(const f16x8*)(&Vt[dt * 16 + lr][lg * 8]);
      f16x8 vb = *(const f16x8*)(&Vt[dt * 16 + lr][32 + lg * 8]);
      cacc[dt] = __builtin_amdgcn_mfma_f32_16x16x32_f16(pa0, va, cacc[dt], 0, 0, 0);
      cacc[dt] = __builtin_amdgcn_mfma_f32_16x16x32_f16(pa1, vb, cacc[dt], 0, 0, 0);
    }

    __syncthreads();                 // all waves done reading Ks & Vt
    if (pre) {                       // write-late: loads long since complete
#pragma unroll
      for (int i = 0; i < 8; ++i) *(f16x8*)(klds + i * 8 * 264) = kreg[i];
#pragma unroll
      for (int i = 0; i < 8; ++i) *(f16x8*)(vlds + (size_t)i * 32 * 72) = vreg[i];
    }
    __syncthreads();                 // staged tile visible
  }

  // ---- epilogue: UNNORMALIZED partial ctx (f16) + m/l (f32) ---------------
  const size_t Rbase = (size_t)b * SEQ + q0 + w * 16;
#pragma unroll
  for (int j = 0; j < 4; ++j) {
    size_t R = Rbase + lg * 4 + j;
    if (lr == 0) {
      Mp[(size_t)split * RROWS + R] = mrun[j];
      Lp[(size_t)split * RROWS + R] = lrun[j];
    }
#pragma unroll
    for (int dt = 0; dt < 16; ++dt)
      Op[((size_t)split * RROWS + R) * DD + dt * 16 + lr] = (_Float16)cacc[dt][j];
  }
}

// ---------------------------------------------------------------------------
// Combine the NSPLIT partials.
// ---------------------------------------------------------------------------
__global__ __launch_bounds__(256) void attn_combine_kernel(
    const _Float16* __restrict__ Op, const float* __restrict__ Mp,
    const float* __restrict__ Lp, _Float16* __restrict__ ctx)
{
  const int lane = threadIdx.x & 63;
  const int w    = threadIdx.x >> 6;
  const size_t R = (size_t)blockIdx.x * 4 + w;
  float m0 = Mp[R], m1 = Mp[RROWS + R];
  float l0 = Lp[R], l1 = Lp[RROWS + R];
  float ms = fmaxf(m0, m1);
  float w0 = __expf(m0 - ms), w1 = __expf(m1 - ms);
  float linv = 1.0f / (w0 * l0 + w1 * l1);
  w0 *= linv; w1 *= linv;
  f16x4 o0 = *(const f16x4*)&Op[R * DD + lane * 4];
  f16x4 o1 = *(const f16x4*)&Op[((size_t)RROWS + R) * DD + lane * 4];
  f16x4 o;
#pragma unroll
  for (int i = 0; i < 4; ++i)
    o[i] = (_Float16)(w0 * (float)o0[i] + w1 * (float)o1[i]);
  *(f16x4*)&ctx[R * DD + lane * 4] = o;
}

// ---------------------------------------------------------------------------
// LayerNorm over last dim (256). One wave per row, 4 rows per block.
// ---------------------------------------------------------------------------
__global__ __launch_bounds__(256) void ln_kernel(
    const float* __restrict__ H, const float* __restrict__ g,
    const float* __restrict__ b, float* __restrict__ out)
{
  const int lane = threadIdx.x & 63;
  const int w    = threadIdx.x >> 6;
  const int r    = blockIdx.x * 4 + w;
  const size_t rowoff = (size_t)r * DD;
  float4 h4 = *(const float4*)&H[rowoff + lane * 4];
  float s = h4.x + h4.y + h4.z + h4.w;
#pragma unroll
  for (int m = 1; m < 64; m <<= 1) s += __shfl_xor(s, m, 64);
  float mu = s * (1.0f / 256.0f);
  float dx = h4.x - mu, dy = h4.y - mu, dz = h4.z - mu, dw = h4.w - mu;
  float v = dx*dx + dy*dy + dz*dz + dw*dw;
#pragma unroll
  for (int m = 1; m < 64; m <<= 1) v += __shfl_xor(v, m, 64);
  float rs = rsqrtf(v * (1.0f / 256.0f) + 1e-5f);
  float4 g4 = *(const float4*)&g[lane * 4];
  float4 b4 = *(const float4*)&b[lane * 4];
  float4 o;
  o.x = dx * rs * g4.x + b4.x;
  o.y = dy * rs * g4.y + b4.y;
  o.z = dz * rs * g4.z + b4.z;
  o.w = dw * rs * g4.w + b4.w;
  *(float4*)&out[rowoff + lane * 4] = o;
}

// ---------------------------------------------------------------------------
extern "C" void kernel_launch(void* const* d_in, const int* in_sizes, int n_in,
                              void* d_out, int out_size, void* d_ws, size_t ws_size,
                              hipStream_t stream) {
  const float* x  = (const float*)d_in[0];
  const float* Wq = (const float*)d_in[1];
  const float* bq = (const float*)d_in[2];
  const float* Wk = (const float*)d_in[3];
  const float* bk = (const float*)d_in[4];
  const float* Wv = (const float*)d_in[5];
  const float* bv = (const float*)d_in[6];
  const float* Wd = (const float*)d_in[7];
  const float* bd = (const float*)d_in[8];
  const float* g  = (const float*)d_in[9];
  const float* b  = (const float*)d_in[10];
  float* out = (float*)d_out;

  const size_t RD = (size_t)RROWS * DD;         // 4 M elements
  _Float16* ws16 = (_Float16*)d_ws;
  _Float16* xh   = ws16;                        //  8 MB
  _Float16* Qh   = ws16 + RD;                   //  8 MB; later ctx
  _Float16* Kh   = ws16 + 2 * RD;               //  8 MB
  _Float16* VtG  = ws16 + 3 * RD;               //  8 MB, tiled [b][s/64][d][64]
  _Float16* Op   = ws16 + 4 * RD;               // 16 MB
  float*    Hf   = (float*)(ws16 + 4 * RD);     // 16 MB overlays Op (dead)
  float*    Mp   = (float*)(ws16 + 6 * RD);     // 128 KB
  float*    Lp   = Mp + (size_t)NSPLIT * RROWS; // 128 KB
  _Float16* Wh   = (_Float16*)(Lp + (size_t)NSPLIT * RROWS);  // 512 KB
  _Float16* ctxh = Qh;

  cast_x_kernel<<<2048, 256, 0, stream>>>(x, xh);
  cast_w_kernel<<<dim3(32, 4), 256, 0, stream>>>(Wq, Wk, Wv, Wd, Wh);

  dim3 gg(RROWS / 64, DD / 128);   // (256, 2)
  gemm16_kernel<1><<<gg, 256, 0, stream>>>(xh, Wh,             bq, nullptr, Qh);
  gemm16_kernel<1><<<gg, 256, 0, stream>>>(xh, Wh + 65536,     bk, nullptr, Kh);
  gemm16_kernel<2><<<gg, 256, 0, stream>>>(xh, Wh + 2 * 65536, bv, nullptr, VtG);

  attn_partial_kernel<<<dim3((SEQ / QBLK) * NSPLIT * NB), 256, 0, stream>>>(
      Qh, Kh, VtG, Op, Mp, Lp);
  attn_combine_kernel<<<RROWS / 4, 256, 0, stream>>>(Op, Mp, Lp, ctxh);

  gemm16_kernel<0><<<gg, 256, 0, stream>>>(ctxh, Wh + 3 * 65536, bd, x, Hf);

  ln_kernel<<<RROWS / 4, 256, 0, stream>>>(Hf, g, b, out);
}

// Round 13
// 118.540 us; speedup vs baseline: 1.6964x; 1.0574x over previous
//
#include <hip/hip_runtime.h>
#include <hip/hip_bf16.h>
#include <hip/hip_fp16.h>
#include <cstdint>

// B=8, S=2048, D=256 fused attention block, fp32 in/out.
// Round 13: attack the LDS pipe (measured bottleneck):
//   - K/V staged via global_load_lds (no reg round-trip, no ds_write staging)
//   - K/V stored PRE-SWIZZLED in global (16B-granule XOR by row&7) so the
//     linear LDS image is bank-conflict-free for QK and PV ds_read_b128
//   - double-buffered K/V LDS, ONE barrier per tile
//   - 8-wave blocks QBLK=128 (halves staging instances), KVBLK=64, NSPLIT=2
// GEMM/LN/cast stages as round 12 except K->MODE3 (swizzled), V MODE2 adds
// the granule swizzle.

#define RROWS 16384
#define DD 256
#define SEQ 2048
#define NB 8
#define NSPLIT 2
#define QBLK 128
#define KVBLK 64
#define NT_SPLIT (SEQ / KVBLK / NSPLIT)   // 16 tiles per split
#define NTILES (SEQ / KVBLK)              // 32 V s-tiles per batch

typedef _Float16 f16x8 __attribute__((ext_vector_type(8)));
typedef _Float16 f16x4 __attribute__((ext_vector_type(4)));
typedef float f32x4 __attribute__((ext_vector_type(4)));

// ---------------------------------------------------------------------------
// casts
// ---------------------------------------------------------------------------
__global__ __launch_bounds__(256) void cast_x_kernel(
    const float* __restrict__ src, _Float16* __restrict__ dst)
{
  const size_t i = ((size_t)blockIdx.x * 256 + threadIdx.x) * 8;
  float4 a = *(const float4*)&src[i];
  float4 b = *(const float4*)&src[i + 4];
  f16x8 h = { (_Float16)a.x, (_Float16)a.y, (_Float16)a.z, (_Float16)a.w,
              (_Float16)b.x, (_Float16)b.y, (_Float16)b.z, (_Float16)b.w };
  *(f16x8*)&dst[i] = h;
}

__global__ __launch_bounds__(256) void cast_w_kernel(
    const float* __restrict__ w0, const float* __restrict__ w1,
    const float* __restrict__ w2, const float* __restrict__ w3,
    _Float16* __restrict__ dst)
{
  const float* srcs[4] = {w0, w1, w2, w3};
  const float* src = srcs[blockIdx.y];
  _Float16* d = dst + (size_t)blockIdx.y * 65536;
  const size_t i = ((size_t)blockIdx.x * 256 + threadIdx.x) * 8;
  float4 a = *(const float4*)&src[i];
  float4 b = *(const float4*)&src[i + 4];
  f16x8 h = { (_Float16)a.x, (_Float16)a.y, (_Float16)a.z, (_Float16)a.w,
              (_Float16)b.x, (_Float16)b.y, (_Float16)b.z, (_Float16)b.w };
  *(f16x8*)&d[i] = h;
}

// ---------------------------------------------------------------------------
// fp16 MFMA GEMM: 64x128 tile, K=256.
// MODE 0: f32 out + res.          MODE 1: f16 row-major (Q).
// MODE 2: f16 TILED [b][s/64][256 d][64 s] with granule swizzle (V).
// MODE 3: f16 row-major with granule swizzle (K):
//         elem(r,c) -> r*256 + (((c>>3) ^ (r&7))<<3) + (c&7).
// ---------------------------------------------------------------------------
template <int MODE>
__global__ __launch_bounds__(256) void gemm16_kernel(
    const _Float16* __restrict__ X, const _Float16* __restrict__ W,
    const float* __restrict__ bias, const float* __restrict__ res,
    void* __restrict__ outv)
{
  __shared__ _Float16 smem[128 * 264];
  const int t     = threadIdx.x;
  const int lane  = t & 63;
  const int w     = t >> 6;
  const int rows0 = blockIdx.x * 64;
  const int col0  = blockIdx.y * 128;
  const int lr = lane & 15;
  const int lg = lane >> 4;

#pragma unroll
  for (int i = 0; i < 16; ++i) {
    int ch = i * 256 + t;
    int er = ch >> 5, kc = (ch & 31) * 8;
    *(f16x8*)&smem[er * 264 + kc] = *(const f16x8*)&W[(size_t)(col0 + er) * DD + kc];
  }

  f16x8 qf[8];
  {
    const _Float16* xrow = X + (size_t)(rows0 + w * 16 + lr) * DD;
#pragma unroll
    for (int ks = 0; ks < 8; ++ks)
      qf[ks] = *(const f16x8*)(xrow + ks * 32 + lg * 8);
  }
  __syncthreads();

  f32x4 acc[8];
#pragma unroll
  for (int i = 0; i < 8; ++i) acc[i] = (f32x4){0.f, 0.f, 0.f, 0.f};

#pragma unroll
  for (int ct = 0; ct < 8; ++ct)
#pragma unroll
    for (int ks = 0; ks < 8; ++ks) {
      f16x8 wf = *(const f16x8*)&smem[(ct * 16 + lr) * 264 + ks * 32 + lg * 8];
      acc[ct] = __builtin_amdgcn_mfma_f32_16x16x32_f16(qf[ks], wf, acc[ct], 0, 0, 0);
    }

  float bf[8];
#pragma unroll
  for (int ct = 0; ct < 8; ++ct) bf[ct] = bias[col0 + ct * 16 + lr];

  if constexpr (MODE == 0) {
    float* out = (float*)outv;
#pragma unroll
    for (int ct = 0; ct < 8; ++ct)
#pragma unroll
      for (int j = 0; j < 4; ++j) {
        int r = rows0 + w * 16 + lg * 4 + j;
        int c = col0 + ct * 16 + lr;
        out[(size_t)r * DD + c] = acc[ct][j] + bf[ct] + res[(size_t)r * DD + c];
      }
  } else if constexpr (MODE == 1) {
    _Float16* out = (_Float16*)outv;
#pragma unroll
    for (int ct = 0; ct < 8; ++ct)
#pragma unroll
      for (int j = 0; j < 4; ++j) {
        int r = rows0 + w * 16 + lg * 4 + j;
        out[(size_t)r * DD + col0 + ct * 16 + lr] = (_Float16)(acc[ct][j] + bf[ct]);
      }
  } else if constexpr (MODE == 3) {   // K: row-major + granule swizzle
    _Float16* out = (_Float16*)outv;
#pragma unroll
    for (int ct = 0; ct < 8; ++ct)
#pragma unroll
      for (int j = 0; j < 4; ++j) {
        int r = rows0 + w * 16 + lg * 4 + j;
        int c = col0 + ct * 16 + lr;
        out[(size_t)r * DD + (((c >> 3) ^ (r & 7)) << 3) + (c & 7)] =
            (_Float16)(acc[ct][j] + bf[ct]);
      }
  } else {  // MODE 2: tiled V^T [b][s/64][256 d][64 s] + granule swizzle
    __syncthreads();
    _Float16* T = smem;   // reuse: [128 e][72 s-pitch]
#pragma unroll
    for (int ct = 0; ct < 8; ++ct)
#pragma unroll
      for (int j = 0; j < 4; ++j)
        T[(ct * 16 + lr) * 72 + (w * 16 + lg * 4 + j)] = (_Float16)(acc[ct][j] + bf[ct]);
    __syncthreads();
    _Float16* out = (_Float16*)outv;
    const int bIdx = rows0 >> 11;
    const int tIdx = (rows0 & (SEQ - 1)) >> 6;
    _Float16* base = out + (((size_t)bIdx * NTILES + tIdx) * DD + col0) * KVBLK;
#pragma unroll
    for (int p = 0; p < 4; ++p) {
      int ch = p * 256 + t;
      int e = ch >> 3, sc = (ch & 7) * 8;          // sc multiple of 8
      int g = (sc >> 3) ^ (e & 7);                 // swizzled 16B granule
      *(f16x8*)&base[(size_t)e * KVBLK + (g << 3)] = *(const f16x8*)&T[e * 72 + sc];
    }
  }
}

// ---------------------------------------------------------------------------
// Split-K MFMA flash attention, v4 (LDS-pipe diet).
// Block = 512 thr (8 waves), QBLK=128 (wave w owns rows q0+w*16..+15),
// KVBLK=64, NSPLIT=2. 1-D grid of 256, lid&7 = batch (XCD L2 locality).
// K/V staged via global_load_lds into double-buffered linear LDS; global
// layouts are pre-swizzled so LDS reads are ~conflict-free. One barrier/tile.
// ---------------------------------------------------------------------------
__global__ __launch_bounds__(512, 2) void attn_partial_kernel(
    const _Float16* __restrict__ Q, const _Float16* __restrict__ K,
    const _Float16* __restrict__ VT, _Float16* __restrict__ Op,
    float* __restrict__ Mp, float* __restrict__ Lp)
{
  __shared__ _Float16 Ks[2][KVBLK * DD];   // 2 x 32KB, swizzled rows of 512B
  __shared__ _Float16 Vt[2][DD * KVBLK];   // 2 x 32KB, swizzled rows of 128B
  __shared__ _Float16 Ps[8][16][80];       // 20.5KB (pitch 160B, 16B aligned)

  const int t     = threadIdx.x;
  const int lane  = t & 63;
  const int w     = t >> 6;               // wave 0..7
  const int lid   = blockIdx.x;
  const int b     = lid & 7;              // batch == XCD slot
  const int inner = lid >> 3;             // 0..31
  const int split = inner & 1;
  const int q0    = (inner >> 1) * QBLK;
  const int kt0   = split * NT_SPLIT;
  const int lr    = lane & 15;
  const int lg    = lane >> 4;
  const int sw    = lr & 7;               // row-dependent granule XOR

  // Q fragments: wave's 16 rows x K=256 (row-major, unswizzled)
  f16x8 qf[8];
  {
    const _Float16* qrow = Q + (size_t)b * SEQ * DD + (size_t)(q0 + w * 16 + lr) * DD;
#pragma unroll
    for (int ks = 0; ks < 8; ++ks)
      qf[ks] = *(const f16x8*)(qrow + ks * 32 + lg * 8);
  }

  const char* Kb = (const char*)(K + (size_t)b * SEQ * DD);
  const char* Vb = (const char*)(VT + (size_t)b * NTILES * (DD * KVBLK));

  // stage one 32KB K-tile + 32KB V-tile; wave w owns 4KB chunks of each
  auto STAGE = [&](int ktAbs, int buf) {
    const char* kg = Kb + (size_t)ktAbs * (KVBLK * DD) * 2;   // bytes
    const char* vg = Vb + (size_t)ktAbs * (DD * KVBLK) * 2;
    char* kl = (char*)&Ks[buf][0];
    char* vl = (char*)&Vt[buf][0];
#pragma unroll
    for (int i = 0; i < 4; ++i) {
      int off = ((w * 4 + i) << 10) + (lane << 4);
      __builtin_amdgcn_global_load_lds((const void*)(kg + off), (void*)(kl + off),
                                       16, 0, 0);
      __builtin_amdgcn_global_load_lds((const void*)(vg + off), (void*)(vl + off),
                                       16, 0, 0);
    }
  };

  f32x4 cacc[16];
#pragma unroll
  for (int i = 0; i < 16; ++i) cacc[i] = (f32x4){0.f, 0.f, 0.f, 0.f};
  float mrun[4] = {-1e30f, -1e30f, -1e30f, -1e30f};
  float lrun[4] = {0.f, 0.f, 0.f, 0.f};

  STAGE(kt0, 0);
  __syncthreads();                         // implied vmcnt(0): buf0 ready

  int cur = 0;
  for (int kt = 0; kt < NT_SPLIT; ++kt) {
    if (kt + 1 < NT_SPLIT) STAGE(kt0 + kt + 1, cur ^ 1);   // fire-and-forget

    const char* KsC = (const char*)&Ks[cur][0];
    const char* VtC = (const char*)&Vt[cur][0];

    // ---- S = Q.K^T : 4 col-tiles x 8 k-steps (swizzled granule reads) ----
    f32x4 sc[4];
#pragma unroll
    for (int ct = 0; ct < 4; ++ct) sc[ct] = (f32x4){0.f, 0.f, 0.f, 0.f};
#pragma unroll
    for (int ct = 0; ct < 4; ++ct)
#pragma unroll
      for (int ks = 0; ks < 8; ++ks) {
        f16x8 kf = *(const f16x8*)(KsC + ((ct * 16 + lr) << 9)
                                       + (((ks * 4 + lg) ^ sw) << 4));
        sc[ct] = __builtin_amdgcn_mfma_f32_16x16x32_f16(qf[ks], kf, sc[ct], 0, 0, 0);
      }

    // ---- online softmax (lane owns 4 q-rows, 4 k-cols) --------------------
    float scl[4];
#pragma unroll
    for (int j = 0; j < 4; ++j) {
      float tm = fmaxf(fmaxf(sc[0][j], sc[1][j]), fmaxf(sc[2][j], sc[3][j]));
      tm = fmaxf(tm, __shfl_xor(tm, 1, 16));
      tm = fmaxf(tm, __shfl_xor(tm, 2, 16));
      tm = fmaxf(tm, __shfl_xor(tm, 4, 16));
      tm = fmaxf(tm, __shfl_xor(tm, 8, 16));
      float mnew = fmaxf(mrun[j], tm);
      scl[j] = __expf(mrun[j] - mnew);
      float ps = 0.f;
#pragma unroll
      for (int ct = 0; ct < 4; ++ct) {
        float p = __expf(sc[ct][j] - mnew);
        sc[ct][j] = p; ps += p;
      }
      ps += __shfl_xor(ps, 1, 16);
      ps += __shfl_xor(ps, 2, 16);
      ps += __shfl_xor(ps, 4, 16);
      ps += __shfl_xor(ps, 8, 16);
      lrun[j] = lrun[j] * scl[j] + ps;
      mrun[j] = mnew;
    }

    // ---- P -> per-wave LDS tile (fp16) ------------------------------------
#pragma unroll
    for (int ct = 0; ct < 4; ++ct)
#pragma unroll
      for (int j = 0; j < 4; ++j)
        Ps[w][lg * 4 + j][ct * 16 + lr] = (_Float16)sc[ct][j];

    // ---- rescale ctx ------------------------------------------------------
#pragma unroll
    for (int dt = 0; dt < 16; ++dt)
#pragma unroll
      for (int j = 0; j < 4; ++j) cacc[dt][j] *= scl[j];

    // ---- ctx += P.V : swizzled granule reads from Vt ----------------------
    f16x8 pa0 = *(const f16x8*)(&Ps[w][lr][lg * 8]);
    f16x8 pa1 = *(const f16x8*)(&Ps[w][lr][32 + lg * 8]);
#pragma unroll
    for (int dt = 0; dt < 16; ++dt) {
      const char* vrow = VtC + ((dt * 16 + lr) << 7);
      f16x8 va = *(const f16x8*)(vrow + ((lg ^ sw) << 4));
      f16x8 vb = *(const f16x8*)(vrow + (((lg + 4) ^ sw) << 4));
      cacc[dt] = __builtin_amdgcn_mfma_f32_16x16x32_f16(pa0, va, cacc[dt], 0, 0, 0);
      cacc[dt] = __builtin_amdgcn_mfma_f32_16x16x32_f16(pa1, vb, cacc[dt], 0, 0, 0);
    }

    __syncthreads();   // drains vmcnt too: next buffer staged + reads done
    cur ^= 1;
  }

  // ---- epilogue: UNNORMALIZED partial ctx (f16) + m/l (f32) ---------------
  const size_t Rbase = (size_t)b * SEQ + q0 + w * 16;
#pragma unroll
  for (int j = 0; j < 4; ++j) {
    size_t R = Rbase + lg * 4 + j;
    if (lr == 0) {
      Mp[(size_t)split * RROWS + R] = mrun[j];
      Lp[(size_t)split * RROWS + R] = lrun[j];
    }
#pragma unroll
    for (int dt = 0; dt < 16; ++dt)
      Op[((size_t)split * RROWS + R) * DD + dt * 16 + lr] = (_Float16)cacc[dt][j];
  }
}

// ---------------------------------------------------------------------------
// Combine the NSPLIT partials.
// ---------------------------------------------------------------------------
__global__ __launch_bounds__(256) void attn_combine_kernel(
    const _Float16* __restrict__ Op, const float* __restrict__ Mp,
    const float* __restrict__ Lp, _Float16* __restrict__ ctx)
{
  const int lane = threadIdx.x & 63;
  const int w    = threadIdx.x >> 6;
  const size_t R = (size_t)blockIdx.x * 4 + w;
  float m0 = Mp[R], m1 = Mp[RROWS + R];
  float l0 = Lp[R], l1 = Lp[RROWS + R];
  float ms = fmaxf(m0, m1);
  float w0 = __expf(m0 - ms), w1 = __expf(m1 - ms);
  float linv = 1.0f / (w0 * l0 + w1 * l1);
  w0 *= linv; w1 *= linv;
  f16x4 o0 = *(const f16x4*)&Op[R * DD + lane * 4];
  f16x4 o1 = *(const f16x4*)&Op[((size_t)RROWS + R) * DD + lane * 4];
  f16x4 o;
#pragma unroll
  for (int i = 0; i < 4; ++i)
    o[i] = (_Float16)(w0 * (float)o0[i] + w1 * (float)o1[i]);
  *(f16x4*)&ctx[R * DD + lane * 4] = o;
}

// ---------------------------------------------------------------------------
// LayerNorm over last dim (256). One wave per row, 4 rows per block.
// ---------------------------------------------------------------------------
__global__ __launch_bounds__(256) void ln_kernel(
    const float* __restrict__ H, const float* __restrict__ g,
    const float* __restrict__ b, float* __restrict__ out)
{
  const int lane = threadIdx.x & 63;
  const int w    = threadIdx.x >> 6;
  const int r    = blockIdx.x * 4 + w;
  const size_t rowoff = (size_t)r * DD;
  float4 h4 = *(const float4*)&H[rowoff + lane * 4];
  float s = h4.x + h4.y + h4.z + h4.w;
#pragma unroll
  for (int m = 1; m < 64; m <<= 1) s += __shfl_xor(s, m, 64);
  float mu = s * (1.0f / 256.0f);
  float dx = h4.x - mu, dy = h4.y - mu, dz = h4.z - mu, dw = h4.w - mu;
  float v = dx*dx + dy*dy + dz*dz + dw*dw;
#pragma unroll
  for (int m = 1; m < 64; m <<= 1) v += __shfl_xor(v, m, 64);
  float rs = rsqrtf(v * (1.0f / 256.0f) + 1e-5f);
  float4 g4 = *(const float4*)&g[lane * 4];
  float4 b4 = *(const float4*)&b[lane * 4];
  float4 o;
  o.x = dx * rs * g4.x + b4.x;
  o.y = dy * rs * g4.y + b4.y;
  o.z = dz * rs * g4.z + b4.z;
  o.w = dw * rs * g4.w + b4.w;
  *(float4*)&out[rowoff + lane * 4] = o;
}

// ---------------------------------------------------------------------------
extern "C" void kernel_launch(void* const* d_in, const int* in_sizes, int n_in,
                              void* d_out, int out_size, void* d_ws, size_t ws_size,
                              hipStream_t stream) {
  const float* x  = (const float*)d_in[0];
  const float* Wq = (const float*)d_in[1];
  const float* bq = (const float*)d_in[2];
  const float* Wk = (const float*)d_in[3];
  const float* bk = (const float*)d_in[4];
  const float* Wv = (const float*)d_in[5];
  const float* bv = (const float*)d_in[6];
  const float* Wd = (const float*)d_in[7];
  const float* bd = (const float*)d_in[8];
  const float* g  = (const float*)d_in[9];
  const float* b  = (const float*)d_in[10];
  float* out = (float*)d_out;

  const size_t RD = (size_t)RROWS * DD;         // 4 M elements
  _Float16* ws16 = (_Float16*)d_ws;
  _Float16* xh   = ws16;                        //  8 MB
  _Float16* Qh   = ws16 + RD;                   //  8 MB; later ctx
  _Float16* Kh   = ws16 + 2 * RD;               //  8 MB, granule-swizzled rows
  _Float16* VtG  = ws16 + 3 * RD;               //  8 MB, tiled+swizzled
  _Float16* Op   = ws16 + 4 * RD;               // 16 MB
  float*    Hf   = (float*)(ws16 + 4 * RD);     // 16 MB overlays Op (dead)
  float*    Mp   = (float*)(ws16 + 6 * RD);     // 128 KB
  float*    Lp   = Mp + (size_t)NSPLIT * RROWS; // 128 KB
  _Float16* Wh   = (_Float16*)(Lp + (size_t)NSPLIT * RROWS);  // 512 KB
  _Float16* ctxh = Qh;

  cast_x_kernel<<<2048, 256, 0, stream>>>(x, xh);
  cast_w_kernel<<<dim3(32, 4), 256, 0, stream>>>(Wq, Wk, Wv, Wd, Wh);

  dim3 gg(RROWS / 64, DD / 128);   // (256, 2)
  gemm16_kernel<1><<<gg, 256, 0, stream>>>(xh, Wh,             bq, nullptr, Qh);
  gemm16_kernel<3><<<gg, 256, 0, stream>>>(xh, Wh + 65536,     bk, nullptr, Kh);
  gemm16_kernel<2><<<gg, 256, 0, stream>>>(xh, Wh + 2 * 65536, bv, nullptr, VtG);

  // grid: 16 q-tiles x 2 splits x 8 batches = 256 blocks of 512 threads
  attn_partial_kernel<<<dim3((SEQ / QBLK) * NSPLIT * NB), 512, 0, stream>>>(
      Qh, Kh, VtG, Op, Mp, Lp);
  attn_combine_kernel<<<RROWS / 4, 256, 0, stream>>>(Op, Mp, Lp, ctxh);

  gemm16_kernel<0><<<gg, 256, 0, stream>>>(ctxh, Wh + 3 * 65536, bd, x, Hf);

  ln_kernel<<<RROWS / 4, 256, 0, stream>>>(Hf, g, b, out);
}

// Round 14
// 118.355 us; speedup vs baseline: 1.6991x; 1.0016x over previous
//
#include <hip/hip_runtime.h>
#include <hip/hip_bf16.h>
#include <hip/hip_fp16.h>
#include <cstdint>

// B=8, S=2048, D=256 fused attention block, fp32 in/out.
// Round 14: softmax-segment diet on the round-13 structure:
//   - T13 defer-max (THR=8): skip rescale/max-update when __any says no row
//     grew past m+8. Op stored NORMALIZED (cacc/l) for f16 safety.
//   - T5 s_setprio(1) around both MFMA clusters.
// Everything else identical to round 13 (global_load_lds staging, pre-swizzled
// K/V, double-buffered LDS, 8-wave QBLK=128 blocks, NSPLIT=2, XCD locality).

#define RROWS 16384
#define DD 256
#define SEQ 2048
#define NB 8
#define NSPLIT 2
#define QBLK 128
#define KVBLK 64
#define NT_SPLIT (SEQ / KVBLK / NSPLIT)   // 16 tiles per split
#define NTILES (SEQ / KVBLK)              // 32 V s-tiles per batch

typedef _Float16 f16x8 __attribute__((ext_vector_type(8)));
typedef _Float16 f16x4 __attribute__((ext_vector_type(4)));
typedef float f32x4 __attribute__((ext_vector_type(4)));

// ---------------------------------------------------------------------------
// casts
// ---------------------------------------------------------------------------
__global__ __launch_bounds__(256) void cast_x_kernel(
    const float* __restrict__ src, _Float16* __restrict__ dst)
{
  const size_t i = ((size_t)blockIdx.x * 256 + threadIdx.x) * 8;
  float4 a = *(const float4*)&src[i];
  float4 b = *(const float4*)&src[i + 4];
  f16x8 h = { (_Float16)a.x, (_Float16)a.y, (_Float16)a.z, (_Float16)a.w,
              (_Float16)b.x, (_Float16)b.y, (_Float16)b.z, (_Float16)b.w };
  *(f16x8*)&dst[i] = h;
}

__global__ __launch_bounds__(256) void cast_w_kernel(
    const float* __restrict__ w0, const float* __restrict__ w1,
    const float* __restrict__ w2, const float* __restrict__ w3,
    _Float16* __restrict__ dst)
{
  const float* srcs[4] = {w0, w1, w2, w3};
  const float* src = srcs[blockIdx.y];
  _Float16* d = dst + (size_t)blockIdx.y * 65536;
  const size_t i = ((size_t)blockIdx.x * 256 + threadIdx.x) * 8;
  float4 a = *(const float4*)&src[i];
  float4 b = *(const float4*)&src[i + 4];
  f16x8 h = { (_Float16)a.x, (_Float16)a.y, (_Float16)a.z, (_Float16)a.w,
              (_Float16)b.x, (_Float16)b.y, (_Float16)b.z, (_Float16)b.w };
  *(f16x8*)&d[i] = h;
}

// ---------------------------------------------------------------------------
// fp16 MFMA GEMM: 64x128 tile, K=256.
// MODE 0: f32 out + res.          MODE 1: f16 row-major (Q).
// MODE 2: f16 TILED [b][s/64][256 d][64 s] with granule swizzle (V).
// MODE 3: f16 row-major with granule swizzle (K):
//         elem(r,c) -> r*256 + (((c>>3) ^ (r&7))<<3) + (c&7).
// ---------------------------------------------------------------------------
template <int MODE>
__global__ __launch_bounds__(256) void gemm16_kernel(
    const _Float16* __restrict__ X, const _Float16* __restrict__ W,
    const float* __restrict__ bias, const float* __restrict__ res,
    void* __restrict__ outv)
{
  __shared__ _Float16 smem[128 * 264];
  const int t     = threadIdx.x;
  const int lane  = t & 63;
  const int w     = t >> 6;
  const int rows0 = blockIdx.x * 64;
  const int col0  = blockIdx.y * 128;
  const int lr = lane & 15;
  const int lg = lane >> 4;

#pragma unroll
  for (int i = 0; i < 16; ++i) {
    int ch = i * 256 + t;
    int er = ch >> 5, kc = (ch & 31) * 8;
    *(f16x8*)&smem[er * 264 + kc] = *(const f16x8*)&W[(size_t)(col0 + er) * DD + kc];
  }

  f16x8 qf[8];
  {
    const _Float16* xrow = X + (size_t)(rows0 + w * 16 + lr) * DD;
#pragma unroll
    for (int ks = 0; ks < 8; ++ks)
      qf[ks] = *(const f16x8*)(xrow + ks * 32 + lg * 8);
  }
  __syncthreads();

  f32x4 acc[8];
#pragma unroll
  for (int i = 0; i < 8; ++i) acc[i] = (f32x4){0.f, 0.f, 0.f, 0.f};

#pragma unroll
  for (int ct = 0; ct < 8; ++ct)
#pragma unroll
    for (int ks = 0; ks < 8; ++ks) {
      f16x8 wf = *(const f16x8*)&smem[(ct * 16 + lr) * 264 + ks * 32 + lg * 8];
      acc[ct] = __builtin_amdgcn_mfma_f32_16x16x32_f16(qf[ks], wf, acc[ct], 0, 0, 0);
    }

  float bf[8];
#pragma unroll
  for (int ct = 0; ct < 8; ++ct) bf[ct] = bias[col0 + ct * 16 + lr];

  if constexpr (MODE == 0) {
    float* out = (float*)outv;
#pragma unroll
    for (int ct = 0; ct < 8; ++ct)
#pragma unroll
      for (int j = 0; j < 4; ++j) {
        int r = rows0 + w * 16 + lg * 4 + j;
        int c = col0 + ct * 16 + lr;
        out[(size_t)r * DD + c] = acc[ct][j] + bf[ct] + res[(size_t)r * DD + c];
      }
  } else if constexpr (MODE == 1) {
    _Float16* out = (_Float16*)outv;
#pragma unroll
    for (int ct = 0; ct < 8; ++ct)
#pragma unroll
      for (int j = 0; j < 4; ++j) {
        int r = rows0 + w * 16 + lg * 4 + j;
        out[(size_t)r * DD + col0 + ct * 16 + lr] = (_Float16)(acc[ct][j] + bf[ct]);
      }
  } else if constexpr (MODE == 3) {   // K: row-major + granule swizzle
    _Float16* out = (_Float16*)outv;
#pragma unroll
    for (int ct = 0; ct < 8; ++ct)
#pragma unroll
      for (int j = 0; j < 4; ++j) {
        int r = rows0 + w * 16 + lg * 4 + j;
        int c = col0 + ct * 16 + lr;
        out[(size_t)r * DD + (((c >> 3) ^ (r & 7)) << 3) + (c & 7)] =
            (_Float16)(acc[ct][j] + bf[ct]);
      }
  } else {  // MODE 2: tiled V^T [b][s/64][256 d][64 s] + granule swizzle
    __syncthreads();
    _Float16* T = smem;   // reuse: [128 e][72 s-pitch]
#pragma unroll
    for (int ct = 0; ct < 8; ++ct)
#pragma unroll
      for (int j = 0; j < 4; ++j)
        T[(ct * 16 + lr) * 72 + (w * 16 + lg * 4 + j)] = (_Float16)(acc[ct][j] + bf[ct]);
    __syncthreads();
    _Float16* out = (_Float16*)outv;
    const int bIdx = rows0 >> 11;
    const int tIdx = (rows0 & (SEQ - 1)) >> 6;
    _Float16* base = out + (((size_t)bIdx * NTILES + tIdx) * DD + col0) * KVBLK;
#pragma unroll
    for (int p = 0; p < 4; ++p) {
      int ch = p * 256 + t;
      int e = ch >> 3, sc = (ch & 7) * 8;          // sc multiple of 8
      int g = (sc >> 3) ^ (e & 7);                 // swizzled 16B granule
      *(f16x8*)&base[(size_t)e * KVBLK + (g << 3)] = *(const f16x8*)&T[e * 72 + sc];
    }
  }
}

// ---------------------------------------------------------------------------
// Split-K MFMA flash attention, v5 (defer-max + setprio).
// Block = 512 thr (8 waves), QBLK=128, KVBLK=64, NSPLIT=2.
// 1-D grid of 256, lid&7 = batch (XCD L2 locality).
// K/V staged via global_load_lds into double-buffered linear LDS; global
// layouts pre-swizzled -> conflict-~free ds_read_b128. One barrier/tile.
// T13: rescale only when __any row max grew past m+8. Op stored normalized.
// ---------------------------------------------------------------------------
__global__ __launch_bounds__(512, 2) void attn_partial_kernel(
    const _Float16* __restrict__ Q, const _Float16* __restrict__ K,
    const _Float16* __restrict__ VT, _Float16* __restrict__ Op,
    float* __restrict__ Mp, float* __restrict__ Lp)
{
  __shared__ _Float16 Ks[2][KVBLK * DD];   // 2 x 32KB, swizzled rows of 512B
  __shared__ _Float16 Vt[2][DD * KVBLK];   // 2 x 32KB, swizzled rows of 128B
  __shared__ _Float16 Ps[8][16][80];       // 20.5KB

  const int t     = threadIdx.x;
  const int lane  = t & 63;
  const int w     = t >> 6;               // wave 0..7
  const int lid   = blockIdx.x;
  const int b     = lid & 7;              // batch == XCD slot
  const int inner = lid >> 3;             // 0..31
  const int split = inner & 1;
  const int q0    = (inner >> 1) * QBLK;
  const int kt0   = split * NT_SPLIT;
  const int lr    = lane & 15;
  const int lg    = lane >> 4;
  const int sw    = lr & 7;               // row-dependent granule XOR

  // Q fragments: wave's 16 rows x K=256 (row-major, unswizzled)
  f16x8 qf[8];
  {
    const _Float16* qrow = Q + (size_t)b * SEQ * DD + (size_t)(q0 + w * 16 + lr) * DD;
#pragma unroll
    for (int ks = 0; ks < 8; ++ks)
      qf[ks] = *(const f16x8*)(qrow + ks * 32 + lg * 8);
  }

  const char* Kb = (const char*)(K + (size_t)b * SEQ * DD);
  const char* Vb = (const char*)(VT + (size_t)b * NTILES * (DD * KVBLK));

  // stage one 32KB K-tile + 32KB V-tile; wave w owns 4KB chunks of each
  auto STAGE = [&](int ktAbs, int buf) {
    const char* kg = Kb + (size_t)ktAbs * (KVBLK * DD) * 2;   // bytes
    const char* vg = Vb + (size_t)ktAbs * (DD * KVBLK) * 2;
    char* kl = (char*)&Ks[buf][0];
    char* vl = (char*)&Vt[buf][0];
#pragma unroll
    for (int i = 0; i < 4; ++i) {
      int off = ((w * 4 + i) << 10) + (lane << 4);
      __builtin_amdgcn_global_load_lds((const void*)(kg + off), (void*)(kl + off),
                                       16, 0, 0);
      __builtin_amdgcn_global_load_lds((const void*)(vg + off), (void*)(vl + off),
                                       16, 0, 0);
    }
  };

  f32x4 cacc[16];
#pragma unroll
  for (int i = 0; i < 16; ++i) cacc[i] = (f32x4){0.f, 0.f, 0.f, 0.f};
  float mrun[4] = {-1e30f, -1e30f, -1e30f, -1e30f};
  float lrun[4] = {0.f, 0.f, 0.f, 0.f};

  STAGE(kt0, 0);
  __syncthreads();                         // implied vmcnt(0): buf0 ready

  int cur = 0;
  for (int kt = 0; kt < NT_SPLIT; ++kt) {
    if (kt + 1 < NT_SPLIT) STAGE(kt0 + kt + 1, cur ^ 1);   // fire-and-forget

    const char* KsC = (const char*)&Ks[cur][0];
    const char* VtC = (const char*)&Vt[cur][0];

    // ---- S = Q.K^T : 4 col-tiles x 8 k-steps (swizzled granule reads) ----
    f32x4 sc[4];
#pragma unroll
    for (int ct = 0; ct < 4; ++ct) sc[ct] = (f32x4){0.f, 0.f, 0.f, 0.f};
    __builtin_amdgcn_s_setprio(1);
#pragma unroll
    for (int ct = 0; ct < 4; ++ct)
#pragma unroll
      for (int ks = 0; ks < 8; ++ks) {
        f16x8 kf = *(const f16x8*)(KsC + ((ct * 16 + lr) << 9)
                                       + (((ks * 4 + lg) ^ sw) << 4));
        sc[ct] = __builtin_amdgcn_mfma_f32_16x16x32_f16(qf[ks], kf, sc[ct], 0, 0, 0);
      }
    __builtin_amdgcn_s_setprio(0);

    // ---- online softmax with defer-max (T13) ------------------------------
    float tmv[4];
    int need = 0;
#pragma unroll
    for (int j = 0; j < 4; ++j) {
      float tm = fmaxf(fmaxf(sc[0][j], sc[1][j]), fmaxf(sc[2][j], sc[3][j]));
      tm = fmaxf(tm, __shfl_xor(tm, 1, 16));
      tm = fmaxf(tm, __shfl_xor(tm, 2, 16));
      tm = fmaxf(tm, __shfl_xor(tm, 4, 16));
      tm = fmaxf(tm, __shfl_xor(tm, 8, 16));
      tmv[j] = tm;
      need |= (tm > mrun[j] + 8.f) ? 1 : 0;
    }
    if (__any(need)) {                       // rare after warm-up
#pragma unroll
      for (int j = 0; j < 4; ++j) {
        float mnew = fmaxf(mrun[j], tmv[j]);
        float scl  = __expf(mrun[j] - mnew);
        mrun[j] = mnew;
        lrun[j] *= scl;
#pragma unroll
        for (int dt = 0; dt < 16; ++dt) cacc[dt][j] *= scl;
      }
    }
#pragma unroll
    for (int j = 0; j < 4; ++j) {
      float ps = 0.f;
#pragma unroll
      for (int ct = 0; ct < 4; ++ct) {
        float p = __expf(sc[ct][j] - mrun[j]);   // bounded by e^8
        sc[ct][j] = p; ps += p;
      }
      ps += __shfl_xor(ps, 1, 16);
      ps += __shfl_xor(ps, 2, 16);
      ps += __shfl_xor(ps, 4, 16);
      ps += __shfl_xor(ps, 8, 16);
      lrun[j] += ps;
#pragma unroll
      for (int ct = 0; ct < 4; ++ct)
        Ps[w][lg * 4 + j][ct * 16 + lr] = (_Float16)sc[ct][j];
    }

    // ---- ctx += P.V : swizzled granule reads from Vt ----------------------
    f16x8 pa0 = *(const f16x8*)(&Ps[w][lr][lg * 8]);
    f16x8 pa1 = *(const f16x8*)(&Ps[w][lr][32 + lg * 8]);
    __builtin_amdgcn_s_setprio(1);
#pragma unroll
    for (int dt = 0; dt < 16; ++dt) {
      const char* vrow = VtC + ((dt * 16 + lr) << 7);
      f16x8 va = *(const f16x8*)(vrow + ((lg ^ sw) << 4));
      f16x8 vb = *(const f16x8*)(vrow + (((lg + 4) ^ sw) << 4));
      cacc[dt] = __builtin_amdgcn_mfma_f32_16x16x32_f16(pa0, va, cacc[dt], 0, 0, 0);
      cacc[dt] = __builtin_amdgcn_mfma_f32_16x16x32_f16(pa1, vb, cacc[dt], 0, 0, 0);
    }
    __builtin_amdgcn_s_setprio(0);

    __syncthreads();   // drains vmcnt too: next buffer staged + reads done
    cur ^= 1;
  }

  // ---- epilogue: NORMALIZED partial ctx (f16) + m/l (f32) -----------------
  const size_t Rbase = (size_t)b * SEQ + q0 + w * 16;
#pragma unroll
  for (int j = 0; j < 4; ++j) {
    size_t R = Rbase + lg * 4 + j;
    if (lr == 0) {
      Mp[(size_t)split * RROWS + R] = mrun[j];
      Lp[(size_t)split * RROWS + R] = lrun[j];
    }
    float inv = 1.0f / lrun[j];
#pragma unroll
    for (int dt = 0; dt < 16; ++dt)
      Op[((size_t)split * RROWS + R) * DD + dt * 16 + lr] =
          (_Float16)(cacc[dt][j] * inv);
  }
}

// ---------------------------------------------------------------------------
// Combine the NSPLIT partials (Op are NORMALIZED):
// ctx = (c0*Op0 + c1*Op1) / (c0 + c1),  ci = e^{mi-m*} * li.
// ---------------------------------------------------------------------------
__global__ __launch_bounds__(256) void attn_combine_kernel(
    const _Float16* __restrict__ Op, const float* __restrict__ Mp,
    const float* __restrict__ Lp, _Float16* __restrict__ ctx)
{
  const int lane = threadIdx.x & 63;
  const int w    = threadIdx.x >> 6;
  const size_t R = (size_t)blockIdx.x * 4 + w;
  float m0 = Mp[R], m1 = Mp[RROWS + R];
  float l0 = Lp[R], l1 = Lp[RROWS + R];
  float ms = fmaxf(m0, m1);
  float c0 = __expf(m0 - ms) * l0, c1 = __expf(m1 - ms) * l1;
  float winv = 1.0f / (c0 + c1);
  float w0 = c0 * winv, w1 = c1 * winv;
  f16x4 o0 = *(const f16x4*)&Op[R * DD + lane * 4];
  f16x4 o1 = *(const f16x4*)&Op[((size_t)RROWS + R) * DD + lane * 4];
  f16x4 o;
#pragma unroll
  for (int i = 0; i < 4; ++i)
    o[i] = (_Float16)(w0 * (float)o0[i] + w1 * (float)o1[i]);
  *(f16x4*)&ctx[R * DD + lane * 4] = o;
}

// ---------------------------------------------------------------------------
// LayerNorm over last dim (256). One wave per row, 4 rows per block.
// ---------------------------------------------------------------------------
__global__ __launch_bounds__(256) void ln_kernel(
    const float* __restrict__ H, const float* __restrict__ g,
    const float* __restrict__ b, float* __restrict__ out)
{
  const int lane = threadIdx.x & 63;
  const int w    = threadIdx.x >> 6;
  const int r    = blockIdx.x * 4 + w;
  const size_t rowoff = (size_t)r * DD;
  float4 h4 = *(const float4*)&H[rowoff + lane * 4];
  float s = h4.x + h4.y + h4.z + h4.w;
#pragma unroll
  for (int m = 1; m < 64; m <<= 1) s += __shfl_xor(s, m, 64);
  float mu = s * (1.0f / 256.0f);
  float dx = h4.x - mu, dy = h4.y - mu, dz = h4.z - mu, dw = h4.w - mu;
  float v = dx*dx + dy*dy + dz*dz + dw*dw;
#pragma unroll
  for (int m = 1; m < 64; m <<= 1) v += __shfl_xor(v, m, 64);
  float rs = rsqrtf(v * (1.0f / 256.0f) + 1e-5f);
  float4 g4 = *(const float4*)&g[lane * 4];
  float4 b4 = *(const float4*)&b[lane * 4];
  float4 o;
  o.x = dx * rs * g4.x + b4.x;
  o.y = dy * rs * g4.y + b4.y;
  o.z = dz * rs * g4.z + b4.z;
  o.w = dw * rs * g4.w + b4.w;
  *(float4*)&out[rowoff + lane * 4] = o;
}

// ---------------------------------------------------------------------------
extern "C" void kernel_launch(void* const* d_in, const int* in_sizes, int n_in,
                              void* d_out, int out_size, void* d_ws, size_t ws_size,
                              hipStream_t stream) {
  const float* x  = (const float*)d_in[0];
  const float* Wq = (const float*)d_in[1];
  const float* bq = (const float*)d_in[2];
  const float* Wk = (const float*)d_in[3];
  const float* bk = (const float*)d_in[4];
  const float* Wv = (const float*)d_in[5];
  const float* bv = (const float*)d_in[6];
  const float* Wd = (const float*)d_in[7];
  const float* bd = (const float*)d_in[8];
  const float* g  = (const float*)d_in[9];
  const float* b  = (const float*)d_in[10];
  float* out = (float*)d_out;

  const size_t RD = (size_t)RROWS * DD;         // 4 M elements
  _Float16* ws16 = (_Float16*)d_ws;
  _Float16* xh   = ws16;                        //  8 MB
  _Float16* Qh   = ws16 + RD;                   //  8 MB; later ctx
  _Float16* Kh   = ws16 + 2 * RD;               //  8 MB, granule-swizzled rows
  _Float16* VtG  = ws16 + 3 * RD;               //  8 MB, tiled+swizzled
  _Float16* Op   = ws16 + 4 * RD;               // 16 MB
  float*    Hf   = (float*)(ws16 + 4 * RD);     // 16 MB overlays Op (dead)
  float*    Mp   = (float*)(ws16 + 6 * RD);     // 128 KB
  float*    Lp   = Mp + (size_t)NSPLIT * RROWS; // 128 KB
  _Float16* Wh   = (_Float16*)(Lp + (size_t)NSPLIT * RROWS);  // 512 KB
  _Float16* ctxh = Qh;

  cast_x_kernel<<<2048, 256, 0, stream>>>(x, xh);
  cast_w_kernel<<<dim3(32, 4), 256, 0, stream>>>(Wq, Wk, Wv, Wd, Wh);

  dim3 gg(RROWS / 64, DD / 128);   // (256, 2)
  gemm16_kernel<1><<<gg, 256, 0, stream>>>(xh, Wh,             bq, nullptr, Qh);
  gemm16_kernel<3><<<gg, 256, 0, stream>>>(xh, Wh + 65536,     bk, nullptr, Kh);
  gemm16_kernel<2><<<gg, 256, 0, stream>>>(xh, Wh + 2 * 65536, bv, nullptr, VtG);

  // grid: 16 q-tiles x 2 splits x 8 batches = 256 blocks of 512 threads
  attn_partial_kernel<<<dim3((SEQ / QBLK) * NSPLIT * NB), 512, 0, stream>>>(
      Qh, Kh, VtG, Op, Mp, Lp);
  attn_combine_kernel<<<RROWS / 4, 256, 0, stream>>>(Op, Mp, Lp, ctxh);

  gemm16_kernel<0><<<gg, 256, 0, stream>>>(ctxh, Wh + 3 * 65536, bd, x, Hf);

  ln_kernel<<<RROWS / 4, 256, 0, stream>>>(Hf, g, b, out);
}